// Round 2
// baseline (109.083 us; speedup 1.0000x reference)
//
#include <hip/hip_runtime.h>
#include <math.h>

#define NCLUST 32
#define NPTS   1000000
#define LOG2E  1.4426950408889634f
#define TWO_PI 6.2831853071795864f
#define NBLOCKS 1024
#define SLOT_BASE 64   // ws slot offset (in unsigned words) for per-block partials

// Sync scheme v3 (R3: contended RMWs cost ~+17us; R4: RELEASE stores emit
// buffer_wbl2 and ACQUIRE polls emit buffer_inv + serialized misses, ~+10us):
//   The ONLY cross-block data is 1024 independent aligned dwords, each
//   self-validating (partial = sum of squares => bit31==0; 0xAA poison has
//   bit31==1, contract verified by R3/R4 passes). A single dword needs
//   atomicity only, NOT ordering:
//   - block b: RELAXED agent-scope atomic store into its OWN slot
//     (performed at the coherence point, no wbl2, no waitcnt drain).
//   - block 0: computes Z first (overlaps stragglers), then polls slots with
//     RELAXED agent-scope atomic loads, 4 independent loads per sweep
//     (vmcnt-pipelined, not serialized spins).
//   Progress: all blocks != 0 are independent and retire regardless.
//
// R5: 4 points per grid-stride iteration (two float4 streams) — near-neutral
// (75.6 -> 74.1), so LDS-latency serialization was NOT the bottleneck.
// R6 (this round): __launch_bounds__(256, 4). Theory: bare launch_bounds(256)
// let the register allocator exceed 256 VGPRs (unroll-32 x 4 streams), which
// collapses occupancy to 1 wave/SIMD -> 1024 blocks run in ~4 serial rounds
// with no TLP. Capping at 128 VGPR guarantees 4 waves/SIMD. Natural live set
// (~80 regs) fits in 128 without spills.

__device__ inline void cluster_consts(int t,
                                      const float* __restrict__ means,
                                      const float* __restrict__ chols,
                                      const float* __restrict__ weights,
                                      float& a, float& b, float& c,
                                      float& e, float& f, float& W,
                                      float& L00, float& L10, float& L11,
                                      float& m0, float& m1, float& w) {
    float c00 = chols[t * 4 + 0];
    float c10 = chols[t * 4 + 2];
    float c11 = chols[t * 4 + 3];
    float S00 = fmaf(c00, c00, 1.0f);
    float S10 = c00 * c10;
    float S11 = c10 * c10 + c11 * c11 + 1.0f;
    L00 = sqrtf(S00);
    L10 = S10 / L00;
    L11 = sqrtf(S11 - L10 * L10);
    m0 = means[t * 2 + 0];
    m1 = means[t * 2 + 1];
    w  = weights[t];
    float iL00 = 1.0f / L00;
    float iL11 = 1.0f / L11;
    float Li00 = iL00;
    float Li10 = -L10 * iL00 * iL11;
    float Li11 = iL11;
    const float s = -0.5f * LOG2E;
    a = s * Li00; b = s * Li10; c = s * Li11;
    e = -(2.0f * a * m0 + b * m1);
    f = -(b * m0 + 2.0f * c * m1);
    float g = a * m0 * m0 + b * m0 * m1 + c * m1 * m1;
    float invnorm = 1.0f / (TWO_PI * sqrtf(L00 * L11));
    W = w * invnorm * exp2f(g);
}

__global__ __launch_bounds__(256, 4) void nmsq_fused(const float* __restrict__ X,
                                                     const float* __restrict__ means,
                                                     const float* __restrict__ chols,
                                                     const float* __restrict__ weights,
                                                     unsigned* __restrict__ wsu,
                                                     float* __restrict__ out) {
    __shared__ float4 cc[NCLUST * 2];
    __shared__ float sL00[NCLUST], sL10[NCLUST], sL11[NCLUST];
    __shared__ float sM0[NCLUST], sM1[NCLUST], sW[NCLUST];
    __shared__ float red[4], redZ[4], redS[4];
    const int t = threadIdx.x;

    if (t < NCLUST) {
        float a, b, c, e, f, W, L00, L10, L11, m0, m1, w;
        cluster_consts(t, means, chols, weights, a, b, c, e, f, W,
                       L00, L10, L11, m0, m1, w);
        cc[2 * t]     = make_float4(a, b, c, e);
        cc[2 * t + 1] = make_float4(f, W, 0.0f, 0.0f);
        sL00[t] = L00; sL10[t] = L10; sL11[t] = L11;
        sM0[t] = m0;   sM1[t] = m1;   sW[t] = w;
    }
    __syncthreads();

    const float4* X4 = (const float4*)X;     // 2 points per float4
    const int NV2 = NPTS / 4;                // 250000 "float8" units; thread i
                                             // handles X4[i] and X4[i + NV2]
    const int T = gridDim.x * blockDim.x;

    float acc = 0.0f;
    for (int i = blockIdx.x * blockDim.x + t; i < NV2; i += T) {
        float4 p = X4[i];                    // points A (p.x,p.y), B (p.z,p.w)
        float4 r = X4[i + NV2];              // points C (r.x,r.y), D (r.z,r.w)
        float xxA = p.x * p.x, xyA = p.x * p.y, yyA = p.y * p.y;
        float xxB = p.z * p.z, xyB = p.z * p.w, yyB = p.w * p.w;
        float xxC = r.x * r.x, xyC = r.x * r.y, yyC = r.y * r.y;
        float xxD = r.z * r.z, xyD = r.z * r.w, yyD = r.w * r.w;
        float sA = 0.0f, sB = 0.0f, sC = 0.0f, sD = 0.0f;
        #pragma unroll
        for (int k = 0; k < NCLUST; ++k) {
            float4 c0 = cc[2 * k];
            float4 c1 = cc[2 * k + 1];
            float argA = fmaf(c0.x, xxA, fmaf(c0.y, xyA, fmaf(c0.z, yyA,
                         fmaf(c0.w, p.x, c1.x * p.y))));
            float argB = fmaf(c0.x, xxB, fmaf(c0.y, xyB, fmaf(c0.z, yyB,
                         fmaf(c0.w, p.z, c1.x * p.w))));
            float argC = fmaf(c0.x, xxC, fmaf(c0.y, xyC, fmaf(c0.z, yyC,
                         fmaf(c0.w, r.x, c1.x * r.y))));
            float argD = fmaf(c0.x, xxD, fmaf(c0.y, xyD, fmaf(c0.z, yyD,
                         fmaf(c0.w, r.z, c1.x * r.w))));
            sA = fmaf(c1.y, __builtin_amdgcn_exp2f(argA), sA);
            sB = fmaf(c1.y, __builtin_amdgcn_exp2f(argB), sB);
            sC = fmaf(c1.y, __builtin_amdgcn_exp2f(argC), sC);
            sD = fmaf(c1.y, __builtin_amdgcn_exp2f(argD), sD);
        }
        acc = fmaf(sA, sA, acc);
        acc = fmaf(sB, sB, acc);
        acc = fmaf(sC, sC, acc);
        acc = fmaf(sD, sD, acc);
    }

    #pragma unroll
    for (int off = 32; off > 0; off >>= 1) acc += __shfl_down(acc, off, 64);
    int lane = t & 63, wid = t >> 6;
    if (lane == 0) red[wid] = acc;
    __syncthreads();

    if (t == 0) {
        float partial = red[0] + red[1] + red[2] + red[3];  // >= 0, bit31 == 0
        __hip_atomic_store(&wsu[SLOT_BASE + blockIdx.x], __float_as_uint(partial),
                           __ATOMIC_RELAXED, __HIP_MEMORY_SCOPE_AGENT);
    }
    if (blockIdx.x != 0) return;

    // ---- block 0 only: Z over 1024 (i,j) pairs (overlaps straggler tails) ----
    float zp = 0.0f;
    for (int p = t; p < NCLUST * NCLUST; p += 256) {
        int i = p >> 5, j = p & 31;
        float A = sL00[i] + sL00[j];
        float B = sL10[i] + sL10[j];
        float C = sL11[i] + sL11[j];
        float d0 = sM0[i] - sM0[j];
        float d1 = sM1[i] - sM1[j];
        float iA = 1.0f / A, iC = 1.0f / C;
        float qz = d0 * d0 * iA + d1 * d1 * iC - B * d0 * d1 * iA * iC;
        float zt = __builtin_amdgcn_exp2f(-0.5f * LOG2E * qz) / (TWO_PI * sqrtf(A * C));
        zp = fmaf(zt * sW[i], sW[j], zp);
    }
    #pragma unroll
    for (int off = 32; off > 0; off >>= 1) zp += __shfl_down(zp, off, 64);
    if (lane == 0) redZ[wid] = zp;

    // ---- poll all 1024 partial slots: 4 pipelined loads per sweep ----
    unsigned v0, v1, v2, v3;
    for (;;) {
        v0 = __hip_atomic_load(&wsu[SLOT_BASE + t + 0 * 256],
                               __ATOMIC_RELAXED, __HIP_MEMORY_SCOPE_AGENT);
        v1 = __hip_atomic_load(&wsu[SLOT_BASE + t + 1 * 256],
                               __ATOMIC_RELAXED, __HIP_MEMORY_SCOPE_AGENT);
        v2 = __hip_atomic_load(&wsu[SLOT_BASE + t + 2 * 256],
                               __ATOMIC_RELAXED, __HIP_MEMORY_SCOPE_AGENT);
        v3 = __hip_atomic_load(&wsu[SLOT_BASE + t + 3 * 256],
                               __ATOMIC_RELAXED, __HIP_MEMORY_SCOPE_AGENT);
        if (!((v0 | v1 | v2 | v3) & 0x80000000u)) break;   // all bit31 clear
    }
    float sp = __uint_as_float(v0) + __uint_as_float(v1) +
               __uint_as_float(v2) + __uint_as_float(v3);
    #pragma unroll
    for (int off = 32; off > 0; off >>= 1) sp += __shfl_down(sp, off, 64);
    if (lane == 0) redS[wid] = sp;
    __syncthreads();

    if (t == 0) {
        float Z = redZ[0] + redZ[1] + redZ[2] + redZ[3];
        float S = redS[0] + redS[1] + redS[2] + redS[3];
        out[0] = (logf(Z) - logf(S)) * (1.0f / (float)NPTS);
    }
}

extern "C" void kernel_launch(void* const* d_in, const int* in_sizes, int n_in,
                              void* d_out, int out_size, void* d_ws, size_t ws_size,
                              hipStream_t stream) {
    const float* X       = (const float*)d_in[0];
    const float* means   = (const float*)d_in[1];
    const float* chols   = (const float*)d_in[2];
    const float* weights = (const float*)d_in[3];
    // d_in[4] = it (unused)
    unsigned* wsu = (unsigned*)d_ws;
    float* out = (float*)d_out;

    nmsq_fused<<<NBLOCKS, 256, 0, stream>>>(X, means, chols, weights, wsu, out);
}

// Round 3
// 75.978 us; speedup vs baseline: 1.4357x; 1.4357x over previous
//
#include <hip/hip_runtime.h>
#include <math.h>

#define NCLUST 32
#define NPTS   1000000
#define LOG2E  1.4426950408889634f
#define TWO_PI 6.2831853071795864f
#define NBLOCKS 1024
#define SLOT_BASE 64   // ws slot offset (in unsigned words) for per-block partials

// R6 post-mortem: (256,4) regressed (VGPR 64, ILP loss) -> reverted to bare
// launch_bounds(256). Counters showed VALUBusy=12% (~6us real work), occupancy
// 30% (time-avg), FETCH 55.7MB (~48MB of poll-sweep traffic): the kernel was
// TAIL-bound on block 0's cross-XCD poll, not bandwidth- or compute-bound.
//
// R7 (this round): DELETE the poll. Two stream-ordered kernels:
//   nmsq_main:     1024 blocks; each computes its partial sum over X and does
//                  a plain store into its own slot. No block waits on anything.
//   nmsq_finalize: 1 block; sums 1024 partials, computes Z (recomputing the
//                  32 cluster consts, trivially cheap), writes out.
// HIP guarantees stream-order coherence across kernel boundaries (runtime
// flushes/invalidates L2 between dispatches), so no atomics, no poison
// contract, no visibility subtleties. Costs one graph-serialized launch gap
// (~2-4us) against removing the 20-40us poll tail + its HBM sweep traffic.

__device__ inline void cluster_consts(int t,
                                      const float* __restrict__ means,
                                      const float* __restrict__ chols,
                                      const float* __restrict__ weights,
                                      float& a, float& b, float& c,
                                      float& e, float& f, float& W,
                                      float& L00, float& L10, float& L11,
                                      float& m0, float& m1, float& w) {
    float c00 = chols[t * 4 + 0];
    float c10 = chols[t * 4 + 2];
    float c11 = chols[t * 4 + 3];
    float S00 = fmaf(c00, c00, 1.0f);
    float S10 = c00 * c10;
    float S11 = c10 * c10 + c11 * c11 + 1.0f;
    L00 = sqrtf(S00);
    L10 = S10 / L00;
    L11 = sqrtf(S11 - L10 * L10);
    m0 = means[t * 2 + 0];
    m1 = means[t * 2 + 1];
    w  = weights[t];
    float iL00 = 1.0f / L00;
    float iL11 = 1.0f / L11;
    float Li00 = iL00;
    float Li10 = -L10 * iL00 * iL11;
    float Li11 = iL11;
    const float s = -0.5f * LOG2E;
    a = s * Li00; b = s * Li10; c = s * Li11;
    e = -(2.0f * a * m0 + b * m1);
    f = -(b * m0 + 2.0f * c * m1);
    float g = a * m0 * m0 + b * m0 * m1 + c * m1 * m1;
    float invnorm = 1.0f / (TWO_PI * sqrtf(L00 * L11));
    W = w * invnorm * exp2f(g);
}

__global__ __launch_bounds__(256) void nmsq_main(const float* __restrict__ X,
                                                 const float* __restrict__ means,
                                                 const float* __restrict__ chols,
                                                 const float* __restrict__ weights,
                                                 unsigned* __restrict__ wsu) {
    __shared__ float4 cc[NCLUST * 2];
    __shared__ float red[4];
    const int t = threadIdx.x;

    if (t < NCLUST) {
        float a, b, c, e, f, W, L00, L10, L11, m0, m1, w;
        cluster_consts(t, means, chols, weights, a, b, c, e, f, W,
                       L00, L10, L11, m0, m1, w);
        cc[2 * t]     = make_float4(a, b, c, e);
        cc[2 * t + 1] = make_float4(f, W, 0.0f, 0.0f);
    }
    __syncthreads();

    const float4* X4 = (const float4*)X;     // 2 points per float4
    const int NV2 = NPTS / 4;                // 250000 units; thread i handles
                                             // X4[i] and X4[i + NV2]
    const int T = gridDim.x * blockDim.x;

    float acc = 0.0f;
    for (int i = blockIdx.x * blockDim.x + t; i < NV2; i += T) {
        float4 p = X4[i];                    // points A (p.x,p.y), B (p.z,p.w)
        float4 r = X4[i + NV2];              // points C (r.x,r.y), D (r.z,r.w)
        float xxA = p.x * p.x, xyA = p.x * p.y, yyA = p.y * p.y;
        float xxB = p.z * p.z, xyB = p.z * p.w, yyB = p.w * p.w;
        float xxC = r.x * r.x, xyC = r.x * r.y, yyC = r.y * r.y;
        float xxD = r.z * r.z, xyD = r.z * r.w, yyD = r.w * r.w;
        float sA = 0.0f, sB = 0.0f, sC = 0.0f, sD = 0.0f;
        #pragma unroll
        for (int k = 0; k < NCLUST; ++k) {
            float4 c0 = cc[2 * k];
            float4 c1 = cc[2 * k + 1];
            float argA = fmaf(c0.x, xxA, fmaf(c0.y, xyA, fmaf(c0.z, yyA,
                         fmaf(c0.w, p.x, c1.x * p.y))));
            float argB = fmaf(c0.x, xxB, fmaf(c0.y, xyB, fmaf(c0.z, yyB,
                         fmaf(c0.w, p.z, c1.x * p.w))));
            float argC = fmaf(c0.x, xxC, fmaf(c0.y, xyC, fmaf(c0.z, yyC,
                         fmaf(c0.w, r.x, c1.x * r.y))));
            float argD = fmaf(c0.x, xxD, fmaf(c0.y, xyD, fmaf(c0.z, yyD,
                         fmaf(c0.w, r.z, c1.x * r.w))));
            sA = fmaf(c1.y, __builtin_amdgcn_exp2f(argA), sA);
            sB = fmaf(c1.y, __builtin_amdgcn_exp2f(argB), sB);
            sC = fmaf(c1.y, __builtin_amdgcn_exp2f(argC), sC);
            sD = fmaf(c1.y, __builtin_amdgcn_exp2f(argD), sD);
        }
        acc = fmaf(sA, sA, acc);
        acc = fmaf(sB, sB, acc);
        acc = fmaf(sC, sC, acc);
        acc = fmaf(sD, sD, acc);
    }

    #pragma unroll
    for (int off = 32; off > 0; off >>= 1) acc += __shfl_down(acc, off, 64);
    int lane = t & 63, wid = t >> 6;
    if (lane == 0) red[wid] = acc;
    __syncthreads();

    if (t == 0) {
        wsu[SLOT_BASE + blockIdx.x] = __float_as_uint(red[0] + red[1] + red[2] + red[3]);
    }
}

__global__ __launch_bounds__(256) void nmsq_finalize(const float* __restrict__ means,
                                                     const float* __restrict__ chols,
                                                     const float* __restrict__ weights,
                                                     const unsigned* __restrict__ wsu,
                                                     float* __restrict__ out) {
    __shared__ float sL00[NCLUST], sL10[NCLUST], sL11[NCLUST];
    __shared__ float sM0[NCLUST], sM1[NCLUST], sW[NCLUST];
    __shared__ float redZ[4], redS[4];
    const int t = threadIdx.x;

    if (t < NCLUST) {
        float a, b, c, e, f, W, L00, L10, L11, m0, m1, w;
        cluster_consts(t, means, chols, weights, a, b, c, e, f, W,
                       L00, L10, L11, m0, m1, w);
        sL00[t] = L00; sL10[t] = L10; sL11[t] = L11;
        sM0[t] = m0;   sM1[t] = m1;   sW[t] = w;
    }

    // partial-sum loads (independent of shared init; issue before syncthreads)
    float sp = __uint_as_float(wsu[SLOT_BASE + t + 0 * 256]) +
               __uint_as_float(wsu[SLOT_BASE + t + 1 * 256]) +
               __uint_as_float(wsu[SLOT_BASE + t + 2 * 256]) +
               __uint_as_float(wsu[SLOT_BASE + t + 3 * 256]);
    __syncthreads();

    // Z over 1024 (i,j) pairs
    float zp = 0.0f;
    for (int p = t; p < NCLUST * NCLUST; p += 256) {
        int i = p >> 5, j = p & 31;
        float A = sL00[i] + sL00[j];
        float B = sL10[i] + sL10[j];
        float C = sL11[i] + sL11[j];
        float d0 = sM0[i] - sM0[j];
        float d1 = sM1[i] - sM1[j];
        float iA = 1.0f / A, iC = 1.0f / C;
        float qz = d0 * d0 * iA + d1 * d1 * iC - B * d0 * d1 * iA * iC;
        float zt = __builtin_amdgcn_exp2f(-0.5f * LOG2E * qz) / (TWO_PI * sqrtf(A * C));
        zp = fmaf(zt * sW[i], sW[j], zp);
    }

    int lane = t & 63, wid = t >> 6;
    #pragma unroll
    for (int off = 32; off > 0; off >>= 1) zp += __shfl_down(zp, off, 64);
    if (lane == 0) redZ[wid] = zp;
    #pragma unroll
    for (int off = 32; off > 0; off >>= 1) sp += __shfl_down(sp, off, 64);
    if (lane == 0) redS[wid] = sp;
    __syncthreads();

    if (t == 0) {
        float Z = redZ[0] + redZ[1] + redZ[2] + redZ[3];
        float S = redS[0] + redS[1] + redS[2] + redS[3];
        out[0] = (logf(Z) - logf(S)) * (1.0f / (float)NPTS);
    }
}

extern "C" void kernel_launch(void* const* d_in, const int* in_sizes, int n_in,
                              void* d_out, int out_size, void* d_ws, size_t ws_size,
                              hipStream_t stream) {
    const float* X       = (const float*)d_in[0];
    const float* means   = (const float*)d_in[1];
    const float* chols   = (const float*)d_in[2];
    const float* weights = (const float*)d_in[3];
    // d_in[4] = it (unused)
    unsigned* wsu = (unsigned*)d_ws;
    float* out = (float*)d_out;

    nmsq_main<<<NBLOCKS, 256, 0, stream>>>(X, means, chols, weights, wsu);
    nmsq_finalize<<<1, 256, 0, stream>>>(means, chols, weights, wsu, out);
}

// Round 4
// 72.016 us; speedup vs baseline: 1.5147x; 1.0550x over previous
//
#include <hip/hip_runtime.h>
#include <math.h>

#define NCLUST 32
#define NPTS   1000000
#define LOG2E  1.4426950408889634f
#define TWO_PI 6.2831853071795864f
#define NBLOCKS 1024
#define SLOT_BASE 64   // ws slot offset (in unsigned words) for per-block partials

// Session ledger:
//  R3/R4: contended RMWs +17us; release/acquire (wbl2/inv) +10us -> use
//         RELAXED agent-scope atomics + bit31 self-validation (poison 0xAA..
//         has bit31 set; computed partials are sums of squares, bit31 clear).
//  R5 (74.1us, best): single kernel, 4 points/thread, bare launch_bounds(256).
//  R6 (109us): launch_bounds(256,4) -> VGPR 64, ILP loss, big regression.
//  R7 (76.0us): two-kernel split (no poll) — wash: poll tail was ~free
//         (overlaps stragglers); extra dispatch gap costs ~2us. Reverted.
//  Budget inference: fill 40.5 + harness reset gaps ~17 + main ~16 (of which
//         ~6 VALU-busy) + tail ~1. Attackable: ~10us of stall in main.
//  R8 (this round): R5 structure +
//   (1) X loads hoisted ABOVE consts/__syncthreads (compiler can't move loads
//       across a barrier; ~900cy HBM latency now hides under setup);
//   (2) block-0 poll throttled with s_sleep(8) (~512cy/sweep): R6 counters
//       showed ~48MB of poll sweep FETCH contending with X reads at the
//       coherence point; throttling cuts it ~50x at <=0.2us detect latency.

__device__ inline void cluster_consts(int t,
                                      const float* __restrict__ means,
                                      const float* __restrict__ chols,
                                      const float* __restrict__ weights,
                                      float& a, float& b, float& c,
                                      float& e, float& f, float& W,
                                      float& L00, float& L10, float& L11,
                                      float& m0, float& m1, float& w) {
    float c00 = chols[t * 4 + 0];
    float c10 = chols[t * 4 + 2];
    float c11 = chols[t * 4 + 3];
    float S00 = fmaf(c00, c00, 1.0f);
    float S10 = c00 * c10;
    float S11 = c10 * c10 + c11 * c11 + 1.0f;
    L00 = sqrtf(S00);
    L10 = S10 / L00;
    L11 = sqrtf(S11 - L10 * L10);
    m0 = means[t * 2 + 0];
    m1 = means[t * 2 + 1];
    w  = weights[t];
    float iL00 = 1.0f / L00;
    float iL11 = 1.0f / L11;
    float Li00 = iL00;
    float Li10 = -L10 * iL00 * iL11;
    float Li11 = iL11;
    const float s = -0.5f * LOG2E;
    a = s * Li00; b = s * Li10; c = s * Li11;
    e = -(2.0f * a * m0 + b * m1);
    f = -(b * m0 + 2.0f * c * m1);
    float g = a * m0 * m0 + b * m0 * m1 + c * m1 * m1;
    float invnorm = 1.0f / (TWO_PI * sqrtf(L00 * L11));
    W = w * invnorm * exp2f(g);
}

__global__ __launch_bounds__(256) void nmsq_fused(const float* __restrict__ X,
                                                  const float* __restrict__ means,
                                                  const float* __restrict__ chols,
                                                  const float* __restrict__ weights,
                                                  unsigned* __restrict__ wsu,
                                                  float* __restrict__ out) {
    __shared__ float4 cc[NCLUST * 2];
    __shared__ float sL00[NCLUST], sL10[NCLUST], sL11[NCLUST];
    __shared__ float sM0[NCLUST], sM1[NCLUST], sW[NCLUST];
    __shared__ float red[4], redZ[4], redS[4];
    const int t = threadIdx.x;

    // ---- (1) issue X loads FIRST: no LDS dependence, hide HBM latency ----
    const float4* X4 = (const float4*)X;     // 2 points per float4
    const int NV2 = NPTS / 4;                // 250000; thread handles X4[i], X4[i+NV2]
    const int i = blockIdx.x * blockDim.x + t;
    const bool active = (i < NV2);
    float4 p = make_float4(0.f, 0.f, 0.f, 0.f);
    float4 r = make_float4(0.f, 0.f, 0.f, 0.f);
    if (active) {
        p = X4[i];                           // points A (p.x,p.y), B (p.z,p.w)
        r = X4[i + NV2];                     // points C (r.x,r.y), D (r.z,r.w)
    }

    if (t < NCLUST) {
        float a, b, c, e, f, W, L00, L10, L11, m0, m1, w;
        cluster_consts(t, means, chols, weights, a, b, c, e, f, W,
                       L00, L10, L11, m0, m1, w);
        cc[2 * t]     = make_float4(a, b, c, e);
        cc[2 * t + 1] = make_float4(f, W, 0.0f, 0.0f);
        sL00[t] = L00; sL10[t] = L10; sL11[t] = L11;
        sM0[t] = m0;   sM1[t] = m1;   sW[t] = w;
    }
    __syncthreads();

    float acc = 0.0f;
    if (active) {
        float xxA = p.x * p.x, xyA = p.x * p.y, yyA = p.y * p.y;
        float xxB = p.z * p.z, xyB = p.z * p.w, yyB = p.w * p.w;
        float xxC = r.x * r.x, xyC = r.x * r.y, yyC = r.y * r.y;
        float xxD = r.z * r.z, xyD = r.z * r.w, yyD = r.w * r.w;
        float sA = 0.0f, sB = 0.0f, sC = 0.0f, sD = 0.0f;
        #pragma unroll
        for (int k = 0; k < NCLUST; ++k) {
            float4 c0 = cc[2 * k];
            float4 c1 = cc[2 * k + 1];
            float argA = fmaf(c0.x, xxA, fmaf(c0.y, xyA, fmaf(c0.z, yyA,
                         fmaf(c0.w, p.x, c1.x * p.y))));
            float argB = fmaf(c0.x, xxB, fmaf(c0.y, xyB, fmaf(c0.z, yyB,
                         fmaf(c0.w, p.z, c1.x * p.w))));
            float argC = fmaf(c0.x, xxC, fmaf(c0.y, xyC, fmaf(c0.z, yyC,
                         fmaf(c0.w, r.x, c1.x * r.y))));
            float argD = fmaf(c0.x, xxD, fmaf(c0.y, xyD, fmaf(c0.z, yyD,
                         fmaf(c0.w, r.z, c1.x * r.w))));
            sA = fmaf(c1.y, __builtin_amdgcn_exp2f(argA), sA);
            sB = fmaf(c1.y, __builtin_amdgcn_exp2f(argB), sB);
            sC = fmaf(c1.y, __builtin_amdgcn_exp2f(argC), sC);
            sD = fmaf(c1.y, __builtin_amdgcn_exp2f(argD), sD);
        }
        acc = fmaf(sA, sA, acc);
        acc = fmaf(sB, sB, acc);
        acc = fmaf(sC, sC, acc);
        acc = fmaf(sD, sD, acc);
    }

    #pragma unroll
    for (int off = 32; off > 0; off >>= 1) acc += __shfl_down(acc, off, 64);
    int lane = t & 63, wid = t >> 6;
    if (lane == 0) red[wid] = acc;
    __syncthreads();

    if (t == 0) {
        float partial = red[0] + red[1] + red[2] + red[3];  // >= 0, bit31 == 0
        __hip_atomic_store(&wsu[SLOT_BASE + blockIdx.x], __float_as_uint(partial),
                           __ATOMIC_RELAXED, __HIP_MEMORY_SCOPE_AGENT);
    }
    if (blockIdx.x != 0) return;

    // ---- block 0 only: Z over 1024 (i,j) pairs (overlaps straggler tails) ----
    float zp = 0.0f;
    for (int q = t; q < NCLUST * NCLUST; q += 256) {
        int ii = q >> 5, jj = q & 31;
        float A = sL00[ii] + sL00[jj];
        float B = sL10[ii] + sL10[jj];
        float C = sL11[ii] + sL11[jj];
        float d0 = sM0[ii] - sM0[jj];
        float d1 = sM1[ii] - sM1[jj];
        float iA = 1.0f / A, iC = 1.0f / C;
        float qz = d0 * d0 * iA + d1 * d1 * iC - B * d0 * d1 * iA * iC;
        float zt = __builtin_amdgcn_exp2f(-0.5f * LOG2E * qz) / (TWO_PI * sqrtf(A * C));
        zp = fmaf(zt * sW[ii], sW[jj], zp);
    }
    #pragma unroll
    for (int off = 32; off > 0; off >>= 1) zp += __shfl_down(zp, off, 64);
    if (lane == 0) redZ[wid] = zp;

    // ---- poll all 1024 partial slots: 4 pipelined loads per sweep, ----
    // ---- s_sleep(8) (~512cy) between sweeps to cut coherence traffic ----
    unsigned v0, v1, v2, v3;
    for (;;) {
        v0 = __hip_atomic_load(&wsu[SLOT_BASE + t + 0 * 256],
                               __ATOMIC_RELAXED, __HIP_MEMORY_SCOPE_AGENT);
        v1 = __hip_atomic_load(&wsu[SLOT_BASE + t + 1 * 256],
                               __ATOMIC_RELAXED, __HIP_MEMORY_SCOPE_AGENT);
        v2 = __hip_atomic_load(&wsu[SLOT_BASE + t + 2 * 256],
                               __ATOMIC_RELAXED, __HIP_MEMORY_SCOPE_AGENT);
        v3 = __hip_atomic_load(&wsu[SLOT_BASE + t + 3 * 256],
                               __ATOMIC_RELAXED, __HIP_MEMORY_SCOPE_AGENT);
        if (!((v0 | v1 | v2 | v3) & 0x80000000u)) break;   // all bit31 clear
        __builtin_amdgcn_s_sleep(8);
    }
    float sp = __uint_as_float(v0) + __uint_as_float(v1) +
               __uint_as_float(v2) + __uint_as_float(v3);
    #pragma unroll
    for (int off = 32; off > 0; off >>= 1) sp += __shfl_down(sp, off, 64);
    if (lane == 0) redS[wid] = sp;
    __syncthreads();

    if (t == 0) {
        float Z = redZ[0] + redZ[1] + redZ[2] + redZ[3];
        float S = redS[0] + redS[1] + redS[2] + redS[3];
        out[0] = (logf(Z) - logf(S)) * (1.0f / (float)NPTS);
    }
}

extern "C" void kernel_launch(void* const* d_in, const int* in_sizes, int n_in,
                              void* d_out, int out_size, void* d_ws, size_t ws_size,
                              hipStream_t stream) {
    const float* X       = (const float*)d_in[0];
    const float* means   = (const float*)d_in[1];
    const float* chols   = (const float*)d_in[2];
    const float* weights = (const float*)d_in[3];
    // d_in[4] = it (unused)
    unsigned* wsu = (unsigned*)d_ws;
    float* out = (float*)d_out;

    nmsq_fused<<<NBLOCKS, 256, 0, stream>>>(X, means, chols, weights, wsu, out);
}